// Round 3
// baseline (540.454 us; speedup 1.0000x reference)
//
#include <hip/hip_runtime.h>
#include <hip/hip_bf16.h>
#include <stdint.h>

#define M_DIM 8192
#define K_DIM 4096
#define N_DIM 4096

typedef __attribute__((ext_vector_type(8))) short short8;
typedef __attribute__((ext_vector_type(4))) float floatx4;

// ---------------- fused per-row abs-mean scale + ternary quantize ----------------
__global__ void fused_scale_quant(const float* __restrict__ w, float* __restrict__ scales,
                                  __hip_bfloat16* __restrict__ qb) {
    int row = blockIdx.x;
    const float4* wr = (const float4*)(w + (size_t)row * K_DIM);
    float4 v[4];
    double s = 0.0;
    #pragma unroll
    for (int i = 0; i < 4; i++) {
        v[i] = wr[threadIdx.x + 256 * i];
        s += (double)fabsf(v[i].x) + (double)fabsf(v[i].y) +
             (double)fabsf(v[i].z) + (double)fabsf(v[i].w);
    }
    #pragma unroll
    for (int off = 32; off > 0; off >>= 1) s += __shfl_down(s, off);
    __shared__ double partial[4];
    __shared__ float s_scale;
    int wave = threadIdx.x >> 6;
    if ((threadIdx.x & 63) == 0) partial[wave] = s;
    __syncthreads();
    if (threadIdx.x == 0) {
        double t = partial[0] + partial[1] + partial[2] + partial[3];
        float m = (float)(t / (double)K_DIM);
        m = fmaxf(m, 1e-5f);
        scales[row] = m;
        s_scale = m;
    }
    __syncthreads();
    float sc = s_scale;
    __hip_bfloat16* qr = qb + (size_t)row * K_DIM;
    #pragma unroll
    for (int i = 0; i < 4; i++) {
        float q0 = fminf(fmaxf(rintf(v[i].x / sc), -1.f), 1.f);
        float q1 = fminf(fmaxf(rintf(v[i].y / sc), -1.f), 1.f);
        float q2 = fminf(fmaxf(rintf(v[i].z / sc), -1.f), 1.f);
        float q3 = fminf(fmaxf(rintf(v[i].w / sc), -1.f), 1.f);
        __hip_bfloat16 o[4] = {__float2bfloat16(q0), __float2bfloat16(q1),
                               __float2bfloat16(q2), __float2bfloat16(q3)};
        *(uint2*)(qr + 4 * (threadIdx.x + 256 * i)) = *(uint2*)o;
    }
}

// ---------------- x fp32 -> bf16 ----------------
__global__ void xconv_kernel(const float* __restrict__ x, __hip_bfloat16* __restrict__ xb) {
    size_t v = (size_t)blockIdx.x * blockDim.x + threadIdx.x;
    float4 a = ((const float4*)x)[2 * v];
    float4 b = ((const float4*)x)[2 * v + 1];
    __hip_bfloat16 o[8] = {__float2bfloat16(a.x), __float2bfloat16(a.y),
                           __float2bfloat16(a.z), __float2bfloat16(a.w),
                           __float2bfloat16(b.x), __float2bfloat16(b.y),
                           __float2bfloat16(b.z), __float2bfloat16(b.w)};
    *(uint4*)(xb + 8 * v) = *(uint4*)o;
}

// ---------------- 256x256 8-phase counted-vmcnt bf16 MFMA GEMM ----------------
// v3: LDS/MFMA overlap. 24 ds_read/K-tile (B halves held in regs, read once);
// read-issue pipelined one phase ahead of use; NO blanket lgkmcnt(0) — operand
// waits are compiler-counted, so each cluster's LDS latency hides under the
// previous cluster's MFMA instead of serializing LDS-burst/MFMA-burst.
__device__ __forceinline__ void load16(const void* g, void* l) {
    __builtin_amdgcn_global_load_lds((const __attribute__((address_space(1))) uint32_t*)g,
                                     (__attribute__((address_space(3))) uint32_t*)l, 16, 0, 0);
}

#define BARRIER() do { asm volatile("" ::: "memory"); __builtin_amdgcn_s_barrier(); asm volatile("" ::: "memory"); } while (0)
#define VM4 asm volatile("s_waitcnt vmcnt(4)" ::: "memory")
#define VM0 asm volatile("s_waitcnt vmcnt(0)" ::: "memory")
#define SB0() __builtin_amdgcn_sched_barrier(0)

// LDS map (128 KiB): buf d at d*65536; A half ha at +ha*16384; B half hb at +32768+hb*16384.
// Within a half (128 rows x 64 bf16): chunk p (16B) at p*16, p = row*8 + (chunk ^ (row&7)).
// global_load_lds dest is linear (tid*16); XOR swizzle applied to GLOBAL source (inverse)
// and ds_read address (forward) — rule #21 both-sides.

#define STAGE_A0(d, t) do { load16(gA00 + (t)*64, ldsw + (d)*65536);          load16(gA01 + (t)*64, ldsw + (d)*65536 + 8192); } while (0)
#define STAGE_A1(d, t) do { load16(gA10 + (t)*64, ldsw + (d)*65536 + 16384);  load16(gA11 + (t)*64, ldsw + (d)*65536 + 24576); } while (0)
#define STAGE_B0(d, t) do { load16(gB00 + (t)*64, ldsw + (d)*65536 + 32768);  load16(gB01 + (t)*64, ldsw + (d)*65536 + 40960); } while (0)
#define STAGE_B1(d, t) do { load16(gB10 + (t)*64, ldsw + (d)*65536 + 49152);  load16(gB11 + (t)*64, ldsw + (d)*65536 + 57344); } while (0)

#define RD_A(DST, CUR, HA) do { \
    _Pragma("unroll") for (int mi_ = 0; mi_ < 4; ++mi_) { \
        DST[0][mi_] = *(const short8*)(lds + (CUR)*65536 + (HA)*16384 + aoff0 + mi_*2048); \
        DST[1][mi_] = *(const short8*)(lds + (CUR)*65536 + (HA)*16384 + aoff1 + mi_*2048); \
    } } while (0)

#define RD_B(DST, CUR, HB) do { \
    _Pragma("unroll") for (int ni_ = 0; ni_ < 2; ++ni_) { \
        DST[0][ni_] = *(const short8*)(lds + (CUR)*65536 + 32768 + (HB)*16384 + boff0 + ni_*2048); \
        DST[1][ni_] = *(const short8*)(lds + (CUR)*65536 + 32768 + (HB)*16384 + boff1 + ni_*2048); \
    } } while (0)

#define MFMA_CLUSTER(HA, HB, AF, BF) do { \
    __builtin_amdgcn_s_setprio(1); \
    _Pragma("unroll") for (int mi_ = 0; mi_ < 4; ++mi_) \
    _Pragma("unroll") for (int ni_ = 0; ni_ < 2; ++ni_) \
        acc[HA][HB][mi_][ni_] = __builtin_amdgcn_mfma_f32_16x16x32_bf16(AF[0][mi_], BF[0][ni_], acc[HA][HB][mi_][ni_], 0, 0, 0); \
    _Pragma("unroll") for (int mi_ = 0; mi_ < 4; ++mi_) \
    _Pragma("unroll") for (int ni_ = 0; ni_ < 2; ++ni_) \
        acc[HA][HB][mi_][ni_] = __builtin_amdgcn_mfma_f32_16x16x32_bf16(AF[1][mi_], BF[1][ni_], acc[HA][HB][mi_][ni_], 0, 0, 0); \
    __builtin_amdgcn_s_setprio(0); \
} while (0)

#define RDNEXT(NXT) do { RD_A(aF0, NXT, 0); RD_B(bF0, NXT, 0); } while (0)

// Per-phase: issue next cluster's reads / one STAGE, then barrier, then MFMA.
// p3: VM4 + barrier certifies next tile's staging (all waves), then next tile's
// A0/B0 reads issue so p0's cluster never waits on a fresh LDS burst.
// Hazard audit: every region's reads are CONSUMED (regs landed) >=1 barrier
// before its overwriting STAGE issues; vmcnt ledger: 12 outstanding -> drain 4/tile.
#define FULL_TILE(CUR, SP0, SP1, SP2, SP3, BVM, RDN) do { \
    RD_B(bF1, CUR, 1); SP0; BARRIER(); SB0(); MFMA_CLUSTER(0, 0, aF0, bF0); BARRIER(); \
    RD_A(aF1, CUR, 1); SP1; BARRIER(); SB0(); MFMA_CLUSTER(0, 1, aF0, bF1); BARRIER(); \
                       SP2; BARRIER(); SB0(); MFMA_CLUSTER(1, 0, aF1, bF0); BARRIER(); \
                       SP3; BVM; BARRIER(); RDN; SB0(); MFMA_CLUSTER(1, 1, aF1, bF1); BARRIER(); \
} while (0)

__global__ __launch_bounds__(512, 1) void gemm_kernel(const __hip_bfloat16* __restrict__ xb,
                                                      const __hip_bfloat16* __restrict__ qb,
                                                      const float* __restrict__ scales,
                                                      float* __restrict__ out) {
    __shared__ __align__(16) char smem[131072];
    char* lds = smem;
    const int tid = threadIdx.x;
    const int lane = tid & 63;
    const int wave = tid >> 6;
    const int wr = wave >> 2;   // 2 wave-rows
    const int wc = wave & 3;    // 4 wave-cols

    // XCD swizzle: 512 wgs, 8 XCDs, 64 contiguous per XCD (bijective, 512%8==0)
    int bid = blockIdx.x;
    int swz = (bid & 7) * 64 + (bid >> 3);
    const int m0 = (swz >> 4) * 256;
    const int n0 = (swz & 15) * 256;

    // staging source (inverse-swizzled): thread covers chunks tid and tid+512 of each half
    const int r0 = tid >> 3,         c0 = (tid & 7) ^ (r0 & 7);
    const int r1 = (tid + 512) >> 3, c1 = ((tid + 512) & 7) ^ (r1 & 7);
    const __hip_bfloat16* gA00 = xb + (size_t)(m0 + r0) * K_DIM + c0 * 8;
    const __hip_bfloat16* gA01 = xb + (size_t)(m0 + r1) * K_DIM + c1 * 8;
    const __hip_bfloat16* gA10 = gA00 + (size_t)128 * K_DIM;
    const __hip_bfloat16* gA11 = gA01 + (size_t)128 * K_DIM;
    const __hip_bfloat16* gB00 = qb + (size_t)(n0 + r0) * K_DIM + c0 * 8;
    const __hip_bfloat16* gB01 = qb + (size_t)(n0 + r1) * K_DIM + c1 * 8;
    const __hip_bfloat16* gB10 = gB00 + (size_t)128 * K_DIM;
    const __hip_bfloat16* gB11 = gB01 + (size_t)128 * K_DIM;
    char* ldsw = lds + tid * 16;

    // ds_read offsets: row = 64*wr + 16*mi + lr (A) / 32*wc + 16*ni + lr (B);
    // (row&7)==(lane&7) since the base terms are multiples of 8 -> swizzle lane-only.
    const int lr = lane & 15, lq = lane >> 4, l7 = lane & 7;
    const int sw0 = (lq ^ l7) * 16;
    const int sw1 = ((4 + lq) ^ l7) * 16;
    const int aoff0 = (wr * 64 + lr) * 128 + sw0;
    const int aoff1 = (wr * 64 + lr) * 128 + sw1;
    const int boff0 = (wc * 32 + lr) * 128 + sw0;
    const int boff1 = (wc * 32 + lr) * 128 + sw1;

    floatx4 acc[2][2][4][2] = {};        // [ha][hb][mi][ni] — 128 regs
    short8 aF0[2][4], aF1[2][4];         // A halves, [kk][mi]
    short8 bF0[2][2], bF1[2][2];         // B halves, [kk][ni] — held whole tile

    // prologue: prime stream; tile0 fully resident after vmcnt(4)+barrier; pre-read A0/B0
    STAGE_A0(0, 0); STAGE_B0(0, 0); STAGE_B1(0, 0); STAGE_A1(0, 0);
    STAGE_A0(1, 1); STAGE_B0(1, 1);
    VM4;
    BARRIER();
    RDNEXT(0);

    #pragma unroll 1
    for (int it = 0; it < 31; ++it) {
        const int kt0 = 2 * it;
        FULL_TILE(0, STAGE_B1(1, kt0 + 1), STAGE_A1(1, kt0 + 1),
                     STAGE_A0(0, kt0 + 2), STAGE_B0(0, kt0 + 2), VM4, RDNEXT(1));
        FULL_TILE(1, STAGE_B1(0, kt0 + 2), STAGE_A1(0, kt0 + 2),
                     STAGE_A0(1, kt0 + 3), STAGE_B0(1, kt0 + 3), VM4, RDNEXT(0));
    }
    // tail: tile 62 finishes tile 63's halves then drains fully; tile 63 no issues
    FULL_TILE(0, STAGE_B1(1, 63), STAGE_A1(1, 63), , , VM0, RDNEXT(1));
    FULL_TILE(1, , , , , , );
    VM0;

    // ---- epilogue: per-wave LDS transpose (stride 68, proven pattern), scaled f32 stores ----
    // C/D frag layout: col=lane&15 (N), row=(lane>>4)*4+reg (M).
    float* epi = (float*)(lds + wave * 4352);   // 16 rows x stride 68 floats
    const int cn = lane & 15, qd = lane >> 4;
    float scl[2][2];
    #pragma unroll
    for (int hb = 0; hb < 2; ++hb)
        #pragma unroll
        for (int ni = 0; ni < 2; ++ni)
            scl[hb][ni] = scales[n0 + hb * 128 + wc * 32 + ni * 16 + cn];

    // local col L=0..63 <-> global col n0 + 32*wc + 96*hb + L  (two 128B islands per row)
    const int colb = n0 + wc * 32 + ((cn >= 8) ? (128 + (cn - 8) * 4) : cn * 4);

    #pragma unroll
    for (int ha = 0; ha < 2; ++ha)
        #pragma unroll
        for (int mi = 0; mi < 4; ++mi) {
            #pragma unroll
            for (int hb = 0; hb < 2; ++hb)
                #pragma unroll
                for (int ni = 0; ni < 2; ++ni)
                    #pragma unroll
                    for (int r = 0; r < 4; ++r)
                        epi[(qd * 4 + r) * 68 + hb * 32 + ni * 16 + cn] =
                            acc[ha][hb][mi][ni][r] * scl[hb][ni];
            const int rowb = m0 + ha * 128 + wr * 64 + mi * 16;
            #pragma unroll
            for (int p = 0; p < 4; ++p) {
                float4 vv = *(const float4*)&epi[(p * 4 + qd) * 68 + cn * 4];
                *(float4*)&out[(size_t)(rowb + p * 4 + qd) * N_DIM + colb] = vv;
            }
        }
}

extern "C" void kernel_launch(void* const* d_in, const int* in_sizes, int n_in,
                              void* d_out, int out_size, void* d_ws, size_t ws_size,
                              hipStream_t stream) {
    const float* x = (const float*)d_in[0];
    const float* w = (const float*)d_in[1];
    float* out = (float*)d_out;

    char* ws = (char*)d_ws;
    __hip_bfloat16* xb = (__hip_bfloat16*)ws;
    __hip_bfloat16* qb = (__hip_bfloat16*)(ws + (size_t)M_DIM * K_DIM * 2);
    float* scales = (float*)(ws + (size_t)M_DIM * K_DIM * 2 + (size_t)N_DIM * K_DIM * 2);

    fused_scale_quant<<<N_DIM, 256, 0, stream>>>(w, scales, qb);
    xconv_kernel<<<(M_DIM * K_DIM / 8) / 256, 256, 0, stream>>>(x, xb);
    gemm_kernel<<<(M_DIM / 256) * (N_DIM / 256), 512, 0, stream>>>(xb, qb, scales, out);
}

// Round 6
// 485.605 us; speedup vs baseline: 1.1129x; 1.1129x over previous
//
#include <hip/hip_runtime.h>
#include <hip/hip_bf16.h>
#include <stdint.h>

#define M_DIM 8192
#define K_DIM 4096
#define N_DIM 4096

typedef __attribute__((ext_vector_type(8))) short short8;
typedef __attribute__((ext_vector_type(16))) float floatx16;

// ---------------- fused per-row abs-mean scale + ternary quantize ----------------
__global__ void fused_scale_quant(const float* __restrict__ w, float* __restrict__ scales,
                                  __hip_bfloat16* __restrict__ qb) {
    int row = blockIdx.x;
    const float4* wr = (const float4*)(w + (size_t)row * K_DIM);
    float4 v[4];
    double s = 0.0;
    #pragma unroll
    for (int i = 0; i < 4; i++) {
        v[i] = wr[threadIdx.x + 256 * i];
        s += (double)fabsf(v[i].x) + (double)fabsf(v[i].y) +
             (double)fabsf(v[i].z) + (double)fabsf(v[i].w);
    }
    #pragma unroll
    for (int off = 32; off > 0; off >>= 1) s += __shfl_down(s, off);
    __shared__ double partial[4];
    __shared__ float s_scale;
    int wave = threadIdx.x >> 6;
    if ((threadIdx.x & 63) == 0) partial[wave] = s;
    __syncthreads();
    if (threadIdx.x == 0) {
        double t = partial[0] + partial[1] + partial[2] + partial[3];
        float m = (float)(t / (double)K_DIM);
        m = fmaxf(m, 1e-5f);
        scales[row] = m;
        s_scale = m;
    }
    __syncthreads();
    float sc = s_scale;
    __hip_bfloat16* qr = qb + (size_t)row * K_DIM;
    #pragma unroll
    for (int i = 0; i < 4; i++) {
        float q0 = fminf(fmaxf(rintf(v[i].x / sc), -1.f), 1.f);
        float q1 = fminf(fmaxf(rintf(v[i].y / sc), -1.f), 1.f);
        float q2 = fminf(fmaxf(rintf(v[i].z / sc), -1.f), 1.f);
        float q3 = fminf(fmaxf(rintf(v[i].w / sc), -1.f), 1.f);
        __hip_bfloat16 o[4] = {__float2bfloat16(q0), __float2bfloat16(q1),
                               __float2bfloat16(q2), __float2bfloat16(q3)};
        *(uint2*)(qr + 4 * (threadIdx.x + 256 * i)) = *(uint2*)o;
    }
}

// ---------------- x fp32 -> bf16 ----------------
__global__ void xconv_kernel(const float* __restrict__ x, __hip_bfloat16* __restrict__ xb) {
    size_t v = (size_t)blockIdx.x * blockDim.x + threadIdx.x;
    float4 a = ((const float4*)x)[2 * v];
    float4 b = ((const float4*)x)[2 * v + 1];
    __hip_bfloat16 o[8] = {__float2bfloat16(a.x), __float2bfloat16(a.y),
                           __float2bfloat16(a.z), __float2bfloat16(a.w),
                           __float2bfloat16(b.x), __float2bfloat16(b.y),
                           __float2bfloat16(b.z), __float2bfloat16(b.w)};
    *(uint4*)(xb + 8 * v) = *(uint4*)o;
}

// ---------------- 256x256 8-phase bf16 MFMA GEMM (32x32x16, depth-1 staging) ----------------
// v5: v4's K-split reads (24 ds_read_b128/wave/tile) with a CORRECTED staging
// schedule. K-split means the current buffer is read in ALL 4 phases, so stages
// may only target the RETIRED buffer: while computing tile t (buf b), stage
// tile t+1 into buf b^1 (A0+B0 @p0, A1 @p1, B1 @p2), single vmcnt(0) after
// p3's MFMA. Last pair issued ~2 phases before the wait -> near-zero stall.
// Single fragment set (24 VGPR) — round 3 proved double-buffering spills.
__device__ __forceinline__ void load16(const void* g, void* l) {
    __builtin_amdgcn_global_load_lds((const __attribute__((address_space(1))) uint32_t*)g,
                                     (__attribute__((address_space(3))) uint32_t*)l, 16, 0, 0);
}

#define BARRIER() do { asm volatile("" ::: "memory"); __builtin_amdgcn_s_barrier(); asm volatile("" ::: "memory"); } while (0)
#define VM0 asm volatile("s_waitcnt vmcnt(0)" ::: "memory")
#define MID() do { BARRIER(); asm volatile("s_waitcnt lgkmcnt(0)" ::: "memory"); __builtin_amdgcn_sched_barrier(0); } while (0)

// LDS map (128 KiB): buf d at d*65536; A0 at +0, A1 at +16384, B0 at +32768, B1 at +49152.
// Each half: 128 rows x 64 bf16 (128B/row = 8 chunks); chunk c of row r at slot
// r*8 + (c ^ (r&7)). global_load_lds dest is linear (tid*16); the XOR swizzle is
// applied to the GLOBAL source (inverse) and the ds_read address (forward) — rule #21.

#define STAGE_A0(d, t) do { load16(gA00 + (t)*64, ldsw + (d)*65536);          load16(gA01 + (t)*64, ldsw + (d)*65536 + 8192); } while (0)
#define STAGE_A1(d, t) do { load16(gA10 + (t)*64, ldsw + (d)*65536 + 16384);  load16(gA11 + (t)*64, ldsw + (d)*65536 + 24576); } while (0)
#define STAGE_B0(d, t) do { load16(gB00 + (t)*64, ldsw + (d)*65536 + 32768);  load16(gB01 + (t)*64, ldsw + (d)*65536 + 40960); } while (0)
#define STAGE_B1(d, t) do { load16(gB10 + (t)*64, ldsw + (d)*65536 + 49152);  load16(gB11 + (t)*64, ldsw + (d)*65536 + 57344); } while (0)
#define STAGE_AB0(d, t) do { STAGE_A0(d, t); STAGE_B0(d, t); } while (0)

// Per K-step kk: 4 A-frags (M rows wr*64 + (mt&1)*32 + l31, half mt>>1) and
// 2 B-frags (N rows wc*32 + l31, half nt). Lane's 8 bf16 at k-chunk
// c = kk*2 + (lane>>5), swizzled slot = c ^ (lane&7) (row&7 == lane&7).
#define RD6(CUR, KO) do { \
    aF[0] = *(const short8*)(lds + (CUR)*65536 +     0 + aRow + (KO)); \
    aF[1] = *(const short8*)(lds + (CUR)*65536 +  4096 + aRow + (KO)); \
    aF[2] = *(const short8*)(lds + (CUR)*65536 + 16384 + aRow + (KO)); \
    aF[3] = *(const short8*)(lds + (CUR)*65536 + 20480 + aRow + (KO)); \
    bF[0] = *(const short8*)(lds + (CUR)*65536 + 32768 + bRow + (KO)); \
    bF[1] = *(const short8*)(lds + (CUR)*65536 + 49152 + bRow + (KO)); \
} while (0)

#define MFMA8() do { \
    __builtin_amdgcn_s_setprio(1); \
    _Pragma("unroll") for (int mt_ = 0; mt_ < 4; ++mt_) \
    _Pragma("unroll") for (int nt_ = 0; nt_ < 2; ++nt_) \
        acc[mt_][nt_] = __builtin_amdgcn_mfma_f32_32x32x16_bf16(aF[mt_], bF[nt_], acc[mt_][nt_], 0, 0, 0); \
    __builtin_amdgcn_s_setprio(0); \
    __builtin_amdgcn_sched_barrier(0); \
} while (0)

// Hazard graph (re-derived for K-split): stages target only buf CUR^1, whose
// last reads drained at tile t-1's p3 MID (per-wave lgkmcnt(0)) before its end
// barrier; first overwrite-issue is at tile t's p0 — strictly after. vmcnt(0)
// after p3's MFMA + end barrier certifies tile t+1 resident for ALL waves.
#define FULL_TILE(CUR, SPA, SPB, SPC) do { \
    RD6(CUR, k0); SPA; MID(); MFMA8(); BARRIER(); \
    RD6(CUR, k1); SPB; MID(); MFMA8(); BARRIER(); \
    RD6(CUR, k2); SPC; MID(); MFMA8(); BARRIER(); \
    RD6(CUR, k3);      MID(); MFMA8(); VM0; BARRIER(); \
} while (0)

__global__ __launch_bounds__(512, 1) void gemm_kernel(const __hip_bfloat16* __restrict__ xb,
                                                      const __hip_bfloat16* __restrict__ qb,
                                                      const float* __restrict__ scales,
                                                      float* __restrict__ out) {
    __shared__ __align__(16) char smem[131072];
    char* lds = smem;
    const int tid = threadIdx.x;
    const int lane = tid & 63;
    const int wave = tid >> 6;
    const int wr = wave >> 2;   // 2 wave-rows (M)
    const int wc = wave & 3;    // 4 wave-cols (N)

    // XCD swizzle: 512 wgs, 8 XCDs, 64 contiguous per XCD (bijective, 512%8==0)
    int bid = blockIdx.x;
    int swz = (bid & 7) * 64 + (bid >> 3);
    const int m0 = (swz >> 4) * 256;
    const int n0 = (swz & 15) * 256;

    // staging source (inverse-swizzled): thread covers chunks tid and tid+512 of each half
    const int r0 = tid >> 3,         c0 = (tid & 7) ^ (r0 & 7);
    const int r1 = (tid + 512) >> 3, c1 = ((tid + 512) & 7) ^ (r1 & 7);
    const __hip_bfloat16* gA00 = xb + (size_t)(m0 + r0) * K_DIM + c0 * 8;
    const __hip_bfloat16* gA01 = xb + (size_t)(m0 + r1) * K_DIM + c1 * 8;
    const __hip_bfloat16* gA10 = gA00 + (size_t)128 * K_DIM;
    const __hip_bfloat16* gA11 = gA01 + (size_t)128 * K_DIM;
    const __hip_bfloat16* gB00 = qb + (size_t)(n0 + r0) * K_DIM + c0 * 8;
    const __hip_bfloat16* gB01 = qb + (size_t)(n0 + r1) * K_DIM + c1 * 8;
    const __hip_bfloat16* gB10 = gB00 + (size_t)128 * K_DIM;
    const __hip_bfloat16* gB11 = gB01 + (size_t)128 * K_DIM;
    char* ldsw = lds + tid * 16;

    // per-lane read bases: A rows = wr*64 + (lane&31), B rows = wc*32 + (lane&31)
    const int l31 = lane & 31, l7 = lane & 7, lq5 = lane >> 5;
    const int aRow = (wr * 64 + l31) * 128;
    const int bRow = (wc * 32 + l31) * 128;
    // k-chunk offsets per K-step kk: ((kk*2 + lq5) ^ l7) * 16
    const int k0 = ((0 + lq5) ^ l7) * 16;
    const int k1 = ((2 + lq5) ^ l7) * 16;
    const int k2 = ((4 + lq5) ^ l7) * 16;
    const int k3 = ((6 + lq5) ^ l7) * 16;

    floatx16 acc[4][2] = {};   // [mt][nt] — 128 acc regs
    short8 aF[4], bF[2];       // 24 VGPRs of fragments (single set — no spill)

    // prologue: stage tile 0 into buf0, drain, certify
    STAGE_A0(0, 0); STAGE_B0(0, 0); STAGE_A1(0, 0); STAGE_B1(0, 0);
    VM0;
    BARRIER();

    #pragma unroll 1
    for (int it = 0; it < 31; ++it) {
        const int kt0 = 2 * it;
        FULL_TILE(0, STAGE_AB0(1, kt0 + 1), STAGE_A1(1, kt0 + 1), STAGE_B1(1, kt0 + 1));
        FULL_TILE(1, STAGE_AB0(0, kt0 + 2), STAGE_A1(0, kt0 + 2), STAGE_B1(0, kt0 + 2));
    }
    // peel: tile 62 (stages tile 63 -> buf1), tile 63 (no stages)
    FULL_TILE(0, STAGE_AB0(1, 63), STAGE_A1(1, 63), STAGE_B1(1, 63));
    FULL_TILE(1, , , );

    // ---- epilogue: per-wave LDS transpose (stride 68), scaled coalesced f32 stores ----
    // 32x32 C/D layout (m74/m101): col = lane&31, row = (reg&3) + 8*(reg>>2) + 4*(lane>>5).
    float* epi = (float*)(lds + wave * 8704);   // 32 rows x stride 68 floats
    const int cn = lane & 15, qd = lane >> 4;
    float scl[2];
    #pragma unroll
    for (int nt = 0; nt < 2; ++nt) scl[nt] = scales[n0 + nt * 128 + wc * 32 + l31];

    // local col L=0..63 <-> global col n0 + wc*32 + nt*128 (two 128B islands per row)
    const int colb = n0 + wc * 32 + ((cn >= 8) ? (128 + (cn - 8) * 4) : cn * 4);

    #pragma unroll
    for (int mt = 0; mt < 4; ++mt) {
        // stage 32x64 (scaled) into LDS
        #pragma unroll
        for (int nt = 0; nt < 2; ++nt)
            #pragma unroll
            for (int r = 0; r < 16; ++r) {
                int row = (r & 3) + 8 * (r >> 2) + 4 * lq5;
                epi[row * 68 + nt * 32 + l31] = acc[mt][nt][r] * scl[nt];
            }
        const int rowb = m0 + (mt >> 1) * 128 + wr * 64 + (mt & 1) * 32;
        // read back coalesced: 8 passes of 4 rows x 64 cols (256B contiguous per row)
        #pragma unroll
        for (int p = 0; p < 8; ++p) {
            float4 vv = *(const float4*)&epi[(p * 4 + qd) * 68 + cn * 4];
            *(float4*)&out[(size_t)(rowb + p * 4 + qd) * N_DIM + colb] = vv;
        }
    }
}

extern "C" void kernel_launch(void* const* d_in, const int* in_sizes, int n_in,
                              void* d_out, int out_size, void* d_ws, size_t ws_size,
                              hipStream_t stream) {
    const float* x = (const float*)d_in[0];
    const float* w = (const float*)d_in[1];
    float* out = (float*)d_out;

    char* ws = (char*)d_ws;
    __hip_bfloat16* xb = (__hip_bfloat16*)ws;
    __hip_bfloat16* qb = (__hip_bfloat16*)(ws + (size_t)M_DIM * K_DIM * 2);
    float* scales = (float*)(ws + (size_t)M_DIM * K_DIM * 2 + (size_t)N_DIM * K_DIM * 2);

    fused_scale_quant<<<N_DIM, 256, 0, stream>>>(w, scales, qb);
    xconv_kernel<<<(M_DIM * K_DIM / 8) / 256, 256, 0, stream>>>(x, xb);
    gemm_kernel<<<(M_DIM / 256) * (N_DIM / 256), 512, 0, stream>>>(xb, qb, scales, out);
}